// Round 6
// baseline (379.518 us; speedup 1.0000x reference)
//
#include <hip/hip_runtime.h>

#define H 768
#define NH 12
#define HD 64
#define BSZ 16
#define SEQ 1024
#define MTOK (BSZ * SEQ)   // 16384
#define N3H (3 * H)        // 2304

typedef __attribute__((ext_vector_type(8))) short bf16x8;
typedef __attribute__((ext_vector_type(4))) float f32x4;
typedef __attribute__((ext_vector_type(16))) float f32x16;
typedef __attribute__((ext_vector_type(8))) unsigned short us8;
typedef __attribute__((ext_vector_type(4))) unsigned short us4;

__device__ __forceinline__ unsigned short f2bf(float f) {
    union { float f; unsigned u; } v; v.f = f;
    unsigned r = v.u + 0x7fffu + ((v.u >> 16) & 1u);   // RNE
    return (unsigned short)(r >> 16);
}

typedef __attribute__((address_space(1))) const unsigned int gu32_t;
typedef __attribute__((address_space(3))) unsigned int lu32_t;
__device__ __forceinline__ void glds16(const void* g, void* l) {
    __builtin_amdgcn_global_load_lds((gu32_t*)g, (lu32_t*)l, 16, 0, 0);
}

// ---------------------------------------------------------------------------
// prep: fused {x fp32->bf16 convert | W_qkv transpose+cvt | W_proj transpose+cvt}
// blocks [0,6144): cvt x ; [6144,6576): W_qkv 36x12 tiles ; [6576,6720): W_proj 12x12
// ---------------------------------------------------------------------------
__global__ __launch_bounds__(256) void prep(
    const float* __restrict__ x,
    const float* __restrict__ Wqkv, const float* __restrict__ Wproj,
    unsigned short* __restrict__ xbf,
    unsigned short* __restrict__ wqkvT, unsigned short* __restrict__ wprojT)
{
    __shared__ float tile[64][65];
    int bx = blockIdx.x, t = threadIdx.x;

    if (bx < 6144) {                      // elementwise convert
        int i = bx * 2048 + t * 8;
        float4 a = *(const float4*)(x + i);
        float4 b = *(const float4*)(x + i + 4);
        us8 o;
        o[0]=f2bf(a.x); o[1]=f2bf(a.y); o[2]=f2bf(a.z); o[3]=f2bf(a.w);
        o[4]=f2bf(b.x); o[5]=f2bf(b.y); o[6]=f2bf(b.z); o[7]=f2bf(b.w);
        *(us8*)(xbf + i) = o;
        return;
    }

    const float* in; unsigned short* out; int Kd, Nd, n0, k0;
    if (bx < 6576) {
        int lb = bx - 6144;
        in = Wqkv; out = wqkvT; Kd = H; Nd = N3H;
        n0 = (lb % 36) * 64; k0 = (lb / 36) * 64;
    } else {
        int lb = bx - 6576;
        in = Wproj; out = wprojT; Kd = H; Nd = H;
        n0 = (lb % 12) * 64; k0 = (lb / 12) * 64;
    }
    #pragma unroll
    for (int r = 0; r < 4; ++r) {
        int kl = r * 16 + (t >> 4);
        float4 v = *(const float4*)(&in[(size_t)(k0 + kl) * Nd + n0 + (t & 15) * 4]);
        tile[kl][(t & 15) * 4 + 0] = v.x; tile[kl][(t & 15) * 4 + 1] = v.y;
        tile[kl][(t & 15) * 4 + 2] = v.z; tile[kl][(t & 15) * 4 + 3] = v.w;
    }
    __syncthreads();
    int nl = t >> 2, kc = (t & 3) * 16;
    us8 o0, o1;
    #pragma unroll
    for (int kk = 0; kk < 8; ++kk) o0[kk] = f2bf(tile[kc + kk][nl]);
    #pragma unroll
    for (int kk = 0; kk < 8; ++kk) o1[kk] = f2bf(tile[kc + 8 + kk][nl]);
    size_t ob = (size_t)(n0 + nl) * Kd + k0 + kc;
    *(us8*)(&out[ob]) = o0;
    *(us8*)(&out[ob + 8]) = o1;
}

// ---------------------------------------------------------------------------
// bf16 MFMA GEMM v6: C[M,N] = A[M,K] @ BT[N,K]^T + bias
// 256x128 tile, BK=64, single-buffer (48 KiB), 4 waves each 64x128,
// 32x32x16 MFMA. global_load_lds(16) with pre-swizzled source.
// Cols < qscale_end scaled by 0.125 in epilogue. XCD chunk swizzle.
// ---------------------------------------------------------------------------
__global__ __launch_bounds__(256) void gemm_bf16(
    const unsigned short* __restrict__ A, const unsigned short* __restrict__ BT,
    const float* __restrict__ bias, void* __restrict__ Cout,
    int M, int N, int K, int write_f32, int qscale_end)
{
    __shared__ char lds[49152];          // A 32K (256 rows) | B 16K (128 rows)
    char* As = lds;
    char* Bs = lds + 32768;
    const char* Ac = (const char*)A;
    const char* Bc = (const char*)BT;
    int t = threadIdx.x;
    int l = t & 63, w = t >> 6;
    int l31 = l & 31, b5 = l >> 5;

    int chunk = (int)gridDim.x >> 3;
    int lin = (blockIdx.x & 7) * chunk + (blockIdx.x >> 3);
    int nbx = N >> 7;
    int bx = lin % nbx, by = lin / nbx;
    int rowBase = by * 256, colBase = bx * 128;

    f32x16 acc[2][4];
    #pragma unroll
    for (int mi = 0; mi < 2; ++mi)
        #pragma unroll
        for (int ni = 0; ni < 4; ++ni)
            #pragma unroll
            for (int r = 0; r < 16; ++r) acc[mi][ni][r] = 0.f;

    for (int k0 = 0; k0 < K; k0 += 64) {
        #pragma unroll
        for (int i = 0; i < 8; ++i) {     // A: 256 rows x 64 k
            int c = t + i * 256;          // 0..2047
            int row = c >> 3;
            int src = ((c & 7) * 16) ^ ((row & 7) << 4);
            glds16(Ac + ((size_t)(rowBase + row) * K + k0) * 2 + src, As + c * 16);
        }
        #pragma unroll
        for (int i = 0; i < 4; ++i) {     // B: 128 rows x 64 k
            int c = t + i * 256;          // 0..1023
            int row = c >> 3;
            int src = ((c & 7) * 16) ^ ((row & 7) << 4);
            glds16(Bc + ((size_t)(colBase + row) * K + k0) * 2 + src, Bs + c * 16);
        }
        asm volatile("s_waitcnt vmcnt(0)" ::: "memory");
        __builtin_amdgcn_s_barrier();

        #pragma unroll
        for (int ks = 0; ks < 4; ++ks) {  // K16 sub-steps
            bf16x8 af[2], bfr[4];
            #pragma unroll
            for (int mi = 0; mi < 2; ++mi) {
                int row = w * 64 + mi * 32 + l31;
                af[mi] = *(const bf16x8*)(As + row * 128 + ((ks * 32 + b5 * 16) ^ ((row & 7) << 4)));
            }
            #pragma unroll
            for (int ni = 0; ni < 4; ++ni) {
                int row = ni * 32 + l31;
                bfr[ni] = *(const bf16x8*)(Bs + row * 128 + ((ks * 32 + b5 * 16) ^ ((row & 7) << 4)));
            }
            #pragma unroll
            for (int mi = 0; mi < 2; ++mi)
                #pragma unroll
                for (int ni = 0; ni < 4; ++ni)
                    acc[mi][ni] = __builtin_amdgcn_mfma_f32_32x32x16_bf16(
                        af[mi], bfr[ni], acc[mi][ni], 0, 0, 0);
        }
        __builtin_amdgcn_s_barrier();
    }

    // epilogue: D col = l31, row = (reg&3) + 8*(reg>>2) + 4*b5
    #pragma unroll
    for (int ni = 0; ni < 4; ++ni) {
        int col = colBase + ni * 32 + l31;
        float bb = bias ? bias[col] : 0.f;
        float mul = (col < qscale_end) ? 0.125f : 1.0f;
        #pragma unroll
        for (int mi = 0; mi < 2; ++mi) {
            #pragma unroll
            for (int reg = 0; reg < 16; ++reg) {
                int row = rowBase + w * 64 + mi * 32 + (reg & 3) + 8 * (reg >> 2) + 4 * b5;
                float v = (acc[mi][ni][reg] + bb) * mul;
                if (write_f32) ((float*)Cout)[(size_t)row * N + col] = v;
                else ((unsigned short*)Cout)[(size_t)row * N + col] = f2bf(v);
            }
        }
    }
}

// ---------------------------------------------------------------------------
// V transpose: qkv bf16 [MTOK][2304] (V part) -> vt bf16 [b][h][d=64][s=1024]
// ---------------------------------------------------------------------------
__global__ __launch_bounds__(256) void vtrans(
    const unsigned short* __restrict__ qkvb, unsigned short* __restrict__ vt)
{
    __shared__ char tile[64 * 128];
    int t = threadIdx.x;
    int st = blockIdx.x, h = blockIdx.y, b = blockIdx.z;
    int s0 = st * 64;
    {
        int s = t >> 2, dc = (t & 3) * 16;
        size_t g = (size_t)(b * SEQ + s0 + s) * N3H + 2 * H + h * HD + dc;
        us8 v0 = *(const us8*)(&qkvb[g]);
        us8 v1 = *(const us8*)(&qkvb[g + 8]);
        *(us8*)(tile + s * 128 + ((dc * 2) ^ ((s & 7) << 4))) = v0;
        *(us8*)(tile + s * 128 + ((dc * 2 + 16) ^ ((s & 7) << 4))) = v1;
    }
    __syncthreads();
    int d = t >> 2, sc = (t & 3) * 16;
    us8 o0, o1;
    #pragma unroll
    for (int kk = 0; kk < 8; ++kk) {
        int s = sc + kk;
        o0[kk] = *(const unsigned short*)(tile + s * 128 + ((d * 2) ^ ((s & 7) << 4)));
    }
    #pragma unroll
    for (int kk = 0; kk < 8; ++kk) {
        int s = sc + 8 + kk;
        o1[kk] = *(const unsigned short*)(tile + s * 128 + ((d * 2) ^ ((s & 7) << 4)));
    }
    size_t ob = ((size_t)((b * NH + h) * 64 + d)) * SEQ + s0 + sc;
    *(us8*)(&vt[ob]) = o0;
    *(us8*)(&vt[ob + 8]) = o1;
}

// ---------------------------------------------------------------------------
// Flash attention v5: 32x32x16 MFMA, 4 waves x 32 q. Q pre-scaled 1/8 in QKV
// epilogue. Subtile-granular causal skip (upper 32-key half dropped when fully
// masked). T13 defer-rescale (THR=8). In-register P re-layout. K/V dbuf via
// global_load_lds(16) + counted vmcnt(4). XCD chunks, heavy-qb first.
// ---------------------------------------------------------------------------
__global__ __launch_bounds__(256, 4) void attn_mfma(
    const unsigned short* __restrict__ qkvb,
    const unsigned short* __restrict__ vt,
    unsigned short* __restrict__ aout)
{
    __shared__ char lds[32768];          // K dbuf 2x8K | V dbuf 2x8K
    char* Kbuf = lds;
    char* Vbuf = lds + 16384;
    int t = threadIdx.x;
    int l = t & 63, w = t >> 6;
    int l31 = l & 31, b5 = l >> 5;

    int lin = ((blockIdx.x & 7) * 192) + (blockIdx.x >> 3);   // XCD chunks
    int qb = 7 - (lin & 7);                                   // heavy first
    int bh = lin >> 3;
    int h = bh % NH, b = bh / NH;

    int wq = qb * 128 + w * 32;          // wave's 32 q rows
    int sw31 = (l31 & 7) << 4;
    int nt = 2 * qb + 2;
    int bhh = b * NH + h;
    const char* qkvc = (const char*)qkvb;
    const char* vtc  = (const char*)vt;

    // Q as B-fragments: col = q = l31, k = d = 16m + b5*8 + j  (pre-scaled)
    bf16x8 qB[4];
    {
        const unsigned short* qrow =
            qkvb + (size_t)(b * SEQ + wq + l31) * N3H + h * HD + b5 * 8;
        #pragma unroll
        for (int m = 0; m < 4; ++m) qB[m] = *(const bf16x8*)(qrow + m * 16);
    }

    auto STAGE = [&](int kt, int bi) {
        #pragma unroll
        for (int i = 0; i < 2; ++i) {
            int c = t + i * 256;
            int row = c >> 3;
            int src = ((c & 7) * 16) ^ ((row & 7) << 4);
            glds16(qkvc + ((size_t)(b * SEQ + kt * 64 + row) * N3H + H + h * HD) * 2 + src,
                   Kbuf + bi * 8192 + c * 16);
        }
        #pragma unroll
        for (int i = 0; i < 2; ++i) {
            int c = t + i * 256;
            int row = c >> 3;
            int src = ((c & 7) * 16) ^ ((row & 7) << 4);
            glds16(vtc + (((size_t)(bhh * 64 + row)) * SEQ + kt * 64) * 2 + src,
                   Vbuf + bi * 8192 + c * 16);
        }
    };

    STAGE(0, 0);
    __syncthreads();   // drains all vmem (Q regs + stage0); clean vmcnt state

    f32x16 o0, o1;
    #pragma unroll
    for (int r = 0; r < 16; ++r) { o0[r] = 0.f; o1[r] = 0.f; }
    float mrun = -1e30f, lrun = 0.f;

    for (int kt = 0; kt < nt; ++kt) {
        int bi = kt & 1;
        if (kt + 1 < nt) {
            STAGE(kt + 1, bi ^ 1);
            asm volatile("s_waitcnt vmcnt(4)" ::: "memory");
        } else {
            asm volatile("s_waitcnt vmcnt(0)" ::: "memory");
        }
        __builtin_amdgcn_s_barrier();

        int ktbase = kt * 64;
        if (ktbase <= wq + 31) {          // wave has unmasked work
            const char* Kb = Kbuf + bi * 8192;
            const char* Vb = Vbuf + bi * 8192;
            bool two = (ktbase + 32 <= wq + 31);   // upper 32-key half live?

            // S^T = K·Q^T : D rows = keys ((r&3)+8*(r>>2)+4*b5), cols = q
            f32x16 s0, s1;
            __builtin_amdgcn_s_setprio(1);
            {
                f32x16 a;
                #pragma unroll
                for (int r = 0; r < 16; ++r) a[r] = 0.f;
                #pragma unroll
                for (int m = 0; m < 4; ++m) {
                    bf16x8 kf = *(const bf16x8*)(Kb + l31 * 128 + ((m * 32 + b5 * 16) ^ sw31));
                    a = __builtin_amdgcn_mfma_f32_32x32x16_bf16(kf, qB[m], a, 0, 0, 0);
                }
                s0 = a;
            }
            if (two) {
                f32x16 a;
                #pragma unroll
                for (int r = 0; r < 16; ++r) a[r] = 0.f;
                #pragma unroll
                for (int m = 0; m < 4; ++m) {
                    bf16x8 kf = *(const bf16x8*)(Kb + (32 + l31) * 128 + ((m * 32 + b5 * 16) ^ sw31));
                    a = __builtin_amdgcn_mfma_f32_32x32x16_bf16(kf, qB[m], a, 0, 0, 0);
                }
                s1 = a;
            }
            __builtin_amdgcn_s_setprio(0);

            int q = wq + l31;
            if (ktbase + 31 > wq) {        // lower half needs masking
                #pragma unroll
                for (int r = 0; r < 16; ++r) {
                    int key = ktbase + (r & 3) + 8 * (r >> 2) + 4 * b5;
                    if (key > q) s0[r] = -3e38f;
                }
            }
            if (two && (ktbase + 63 > wq)) {
                #pragma unroll
                for (int r = 0; r < 16; ++r) {
                    int key = ktbase + 32 + (r & 3) + 8 * (r >> 2) + 4 * b5;
                    if (key > q) s1[r] = -3e38f;
                }
            }

            // online softmax: tree max + 1 xor32; T13 defer-rescale
            float m01 = fmaxf(s0[0], s0[1]), m23 = fmaxf(s0[2], s0[3]);
            float m45 = fmaxf(s0[4], s0[5]), m67 = fmaxf(s0[6], s0[7]);
            float m89 = fmaxf(s0[8], s0[9]), mab = fmaxf(s0[10], s0[11]);
            float mcd = fmaxf(s0[12], s0[13]), mef = fmaxf(s0[14], s0[15]);
            float mx = fmaxf(fmaxf(fmaxf(m01, m23), fmaxf(m45, m67)),
                             fmaxf(fmaxf(m89, mab), fmaxf(mcd, mef)));
            if (two) {
                float n01 = fmaxf(s1[0], s1[1]), n23 = fmaxf(s1[2], s1[3]);
                float n45 = fmaxf(s1[4], s1[5]), n67 = fmaxf(s1[6], s1[7]);
                float n89 = fmaxf(s1[8], s1[9]), nab = fmaxf(s1[10], s1[11]);
                float ncd = fmaxf(s1[12], s1[13]), nef = fmaxf(s1[14], s1[15]);
                mx = fmaxf(mx, fmaxf(fmaxf(fmaxf(n01, n23), fmaxf(n45, n67)),
                                     fmaxf(fmaxf(n89, nab), fmaxf(ncd, nef))));
            }
            mx = fmaxf(mx, __shfl_xor(mx, 32, 64));
            if (!__all(mx - mrun <= 8.f)) {
                float mnew = fmaxf(mrun, mx);
                float sc = __expf(mrun - mnew);
                mrun = mnew;
                lrun *= sc;
                #pragma unroll
                for (int r = 0; r < 16; ++r) { o0[r] *= sc; o1[r] *= sc; }
            }
            float rs = 0.f;
            #pragma unroll
            for (int r = 0; r < 16; ++r) {
                float p = __expf(s0[r] - mrun);
                s0[r] = p;
                rs += p;
            }
            if (two) {
                #pragma unroll
                for (int r = 0; r < 16; ++r) {
                    float p = __expf(s1[r] - mrun);
                    s1[r] = p;
                    rs += p;
                }
            }
            rs += __shfl_xor(rs, 32, 64);
            lrun += rs;

            // P D-layout -> B-fragments, in-register (1 xor32 swap / window)
            bf16x8 pB[4];
            #pragma unroll
            for (int wd = 0; wd < 4; ++wd) {
                if (wd >= 2 && !two) break;
                const f32x16& sv = (wd < 2) ? s0 : s1;
                int hf = (wd & 1) * 8;
                unsigned pk0 = (unsigned)f2bf(sv[hf + 0]) | ((unsigned)f2bf(sv[hf + 1]) << 16);
                unsigned pk1 = (unsigned)f2bf(sv[hf + 2]) | ((unsigned)f2bf(sv[hf + 3]) << 16);
                unsigned pk2 = (unsigned)f2bf(sv[hf + 4]) | ((unsigned)f2bf(sv[hf + 5]) << 16);
                unsigned pk3 = (unsigned)f2bf(sv[hf + 6]) | ((unsigned)f2bf(sv[hf + 7]) << 16);
                unsigned snd0 = b5 ? pk0 : pk2;
                unsigned snd1 = b5 ? pk1 : pk3;
                unsigned r0 = (unsigned)__shfl_xor((int)snd0, 32, 64);
                unsigned r1 = (unsigned)__shfl_xor((int)snd1, 32, 64);
                union { unsigned u[4]; bf16x8 v; } cvt;
                cvt.u[0] = b5 ? r0 : pk0;
                cvt.u[1] = b5 ? r1 : pk1;
                cvt.u[2] = b5 ? pk2 : r0;
                cvt.u[3] = b5 ? pk3 : r1;
                pB[wd] = cvt.v;
            }

            // O^T += V^T · P^T  (windows 2,3 skipped when upper half masked)
            __builtin_amdgcn_s_setprio(1);
            #pragma unroll
            for (int wd = 0; wd < 4; ++wd) {
                if (wd >= 2 && !two) break;
                bf16x8 v0 = *(const bf16x8*)(Vb + l31 * 128 + ((wd * 32 + b5 * 16) ^ sw31));
                o0 = __builtin_amdgcn_mfma_f32_32x32x16_bf16(v0, pB[wd], o0, 0, 0, 0);
                bf16x8 v1 = *(const bf16x8*)(Vb + (32 + l31) * 128 + ((wd * 32 + b5 * 16) ^ sw31));
                o1 = __builtin_amdgcn_mfma_f32_32x32x16_bf16(v1, pB[wd], o1, 0, 0, 0);
            }
            __builtin_amdgcn_s_setprio(0);
        }
        __builtin_amdgcn_s_barrier();
    }

    // epilogue: d = 32*half + 8g + 4b5 + j, q = wq + l31
    float inv = 1.f / lrun;
    size_t tok = (size_t)(b * SEQ + wq + l31);
    #pragma unroll
    for (int g = 0; g < 4; ++g) {
        us4 w0, w1;
        #pragma unroll
        for (int j = 0; j < 4; ++j) {
            w0[j] = f2bf(o0[g * 4 + j] * inv);
            w1[j] = f2bf(o1[g * 4 + j] * inv);
        }
        int d0 = g * 8 + b5 * 4;
        *(us4*)(&aout[tok * H + h * HD + d0]) = w0;
        *(us4*)(&aout[tok * H + h * HD + 32 + d0]) = w1;
    }
}

// ---------------------------------------------------------------------------
extern "C" void kernel_launch(void* const* d_in, const int* in_sizes, int n_in,
                              void* d_out, int out_size, void* d_ws, size_t ws_size,
                              hipStream_t stream) {
    const float* x      = (const float*)d_in[0];
    const float* W_qkv  = (const float*)d_in[1];
    const float* b_qkv  = (const float*)d_in[2];
    const float* W_proj = (const float*)d_in[3];
    const float* b_proj = (const float*)d_in[4];
    float* outp = (float*)d_out;

    char* ws = (char*)d_ws;
    unsigned short* xbf    = (unsigned short*)ws;  ws += (size_t)MTOK * H * 2;
    unsigned short* wqkvT  = (unsigned short*)ws;  ws += (size_t)N3H * H * 2;
    unsigned short* wprojT = (unsigned short*)ws;  ws += (size_t)H * H * 2;
    unsigned short* qkvb   = (unsigned short*)ws;  ws += (size_t)MTOK * N3H * 2;
    unsigned short* vtb    = (unsigned short*)ws;  ws += (size_t)BSZ * NH * 64 * SEQ * 2;
    unsigned short* aob    = (unsigned short*)ws;

    // fused preprocessing: cvt x + transpose/cvt both weights
    prep<<<6720, 256, 0, stream>>>(x, W_qkv, W_proj, xbf, wqkvT, wprojT);

    // QKV: [16384,768] @ [768,2304] -> bf16, Q cols pre-scaled by 0.125
    gemm_bf16<<<(MTOK / 256) * (N3H / 128), 256, 0, stream>>>(
        xbf, wqkvT, b_qkv, qkvb, MTOK, N3H, H, 0, H);

    vtrans<<<dim3(SEQ / 64, NH, BSZ), 256, 0, stream>>>(qkvb, vtb);

    // attention: 1536 blocks, XCD-chunked, heavy-qb first
    attn_mfma<<<(SEQ / 128) * NH * BSZ, 256, 0, stream>>>(qkvb, vtb, aob);

    // proj: [16384,768] @ [768,768] -> fp32 out
    gemm_bf16<<<(MTOK / 256) * (H / 128), 256, 0, stream>>>(
        aob, wprojT, b_proj, (void*)outp, MTOK, H, H, 1, 0);
}

// Round 7
// 318.948 us; speedup vs baseline: 1.1899x; 1.1899x over previous
//
#include <hip/hip_runtime.h>

#define H 768
#define NH 12
#define HD 64
#define BSZ 16
#define SEQ 1024
#define MTOK (BSZ * SEQ)   // 16384
#define N3H (3 * H)        // 2304

typedef __attribute__((ext_vector_type(8))) short bf16x8;
typedef __attribute__((ext_vector_type(4))) float f32x4;
typedef __attribute__((ext_vector_type(16))) float f32x16;
typedef __attribute__((ext_vector_type(8))) unsigned short us8;
typedef __attribute__((ext_vector_type(4))) unsigned short us4;

__device__ __forceinline__ unsigned short f2bf(float f) {
    union { float f; unsigned u; } v; v.f = f;
    unsigned r = v.u + 0x7fffu + ((v.u >> 16) & 1u);   // RNE
    return (unsigned short)(r >> 16);
}

typedef __attribute__((address_space(1))) const unsigned int gu32_t;
typedef __attribute__((address_space(3))) unsigned int lu32_t;
__device__ __forceinline__ void glds16(const void* g, void* l) {
    __builtin_amdgcn_global_load_lds((gu32_t*)g, (lu32_t*)l, 16, 0, 0);
}

// ---------------------------------------------------------------------------
// prep: fused {x fp32->bf16 convert | W_qkv transpose+cvt | W_proj transpose+cvt}
// blocks [0,6144): cvt x ; [6144,6576): W_qkv 36x12 tiles ; [6576,6720): W_proj
// ---------------------------------------------------------------------------
__global__ __launch_bounds__(256) void prep(
    const float* __restrict__ x,
    const float* __restrict__ Wqkv, const float* __restrict__ Wproj,
    unsigned short* __restrict__ xbf,
    unsigned short* __restrict__ wqkvT, unsigned short* __restrict__ wprojT)
{
    __shared__ float tile[64][65];
    int bx = blockIdx.x, t = threadIdx.x;

    if (bx < 6144) {                      // elementwise convert
        int i = bx * 2048 + t * 8;
        float4 a = *(const float4*)(x + i);
        float4 b = *(const float4*)(x + i + 4);
        us8 o;
        o[0]=f2bf(a.x); o[1]=f2bf(a.y); o[2]=f2bf(a.z); o[3]=f2bf(a.w);
        o[4]=f2bf(b.x); o[5]=f2bf(b.y); o[6]=f2bf(b.z); o[7]=f2bf(b.w);
        *(us8*)(xbf + i) = o;
        return;
    }

    const float* in; unsigned short* out; int Kd, Nd, n0, k0;
    if (bx < 6576) {
        int lb = bx - 6144;
        in = Wqkv; out = wqkvT; Kd = H; Nd = N3H;
        n0 = (lb % 36) * 64; k0 = (lb / 36) * 64;
    } else {
        int lb = bx - 6576;
        in = Wproj; out = wprojT; Kd = H; Nd = H;
        n0 = (lb % 12) * 64; k0 = (lb / 12) * 64;
    }
    #pragma unroll
    for (int r = 0; r < 4; ++r) {
        int kl = r * 16 + (t >> 4);
        float4 v = *(const float4*)(&in[(size_t)(k0 + kl) * Nd + n0 + (t & 15) * 4]);
        tile[kl][(t & 15) * 4 + 0] = v.x; tile[kl][(t & 15) * 4 + 1] = v.y;
        tile[kl][(t & 15) * 4 + 2] = v.z; tile[kl][(t & 15) * 4 + 3] = v.w;
    }
    __syncthreads();
    int nl = t >> 2, kc = (t & 3) * 16;
    us8 o0, o1;
    #pragma unroll
    for (int kk = 0; kk < 8; ++kk) o0[kk] = f2bf(tile[kc + kk][nl]);
    #pragma unroll
    for (int kk = 0; kk < 8; ++kk) o1[kk] = f2bf(tile[kc + 8 + kk][nl]);
    size_t ob = (size_t)(n0 + nl) * Kd + k0 + kc;
    *(us8*)(&out[ob]) = o0;
    *(us8*)(&out[ob + 8]) = o1;
}

// ---------------------------------------------------------------------------
// bf16 MFMA GEMM (round-4 proven structure): C[M,N] = A[M,K] @ BT[N,K]^T + bias
// 128x128 tile, BK=64, single 32K LDS buffer, 4 waves (each 64x64), 16x16 MFMA
// (fragment reads span 16 rows -> 2-way LDS aliasing = free; 32-row reads are
// an unavoidable 4-way conflict with 128B rows — round-6 lesson).
// QKV mode (vt != null): V-range cols written transposed to vt ONLY; Q cols
// pre-scaled by 0.125. Proj mode (write_f32): fp32 C.
// ---------------------------------------------------------------------------
__global__ __launch_bounds__(256) void gemm_bf16(
    const unsigned short* __restrict__ A, const unsigned short* __restrict__ BT,
    const float* __restrict__ bias, void* __restrict__ Cout,
    unsigned short* __restrict__ vt,
    int M, int N, int K, int write_f32, int qscale_end)
{
    __shared__ char lds[32768];
    char* As = lds;
    char* Bs = lds + 16384;
    const char* Ac = (const char*)A;
    const char* Bc = (const char*)BT;
    int t = threadIdx.x;
    int l = t & 63, w = t >> 6;
    int l16 = l & 15, l4 = l >> 4;
    int wm = w >> 1, wn = w & 1;

    int chunk = (int)gridDim.x >> 3;
    int lin = (blockIdx.x & 7) * chunk + (blockIdx.x >> 3);
    int nbx = N >> 7;
    int bx = lin % nbx, by = lin / nbx;
    int rowBase = by * 128, colBase = bx * 128;

    f32x4 acc[4][4];
    #pragma unroll
    for (int i = 0; i < 4; ++i)
        #pragma unroll
        for (int j = 0; j < 4; ++j) acc[i][j] = (f32x4){0, 0, 0, 0};

    for (int k0 = 0; k0 < K; k0 += 64) {
        #pragma unroll
        for (int i = 0; i < 4; ++i) {
            int c = t + i * 256;             // 0..1023
            int row = c >> 3;
            int src = ((c & 7) * 16) ^ ((row & 7) << 4);
            glds16(Ac + ((size_t)(rowBase + row) * K + k0) * 2 + src, As + c * 16);
            glds16(Bc + ((size_t)(colBase + row) * K + k0) * 2 + src, Bs + c * 16);
        }
        asm volatile("s_waitcnt vmcnt(0)" ::: "memory");
        __builtin_amdgcn_s_barrier();

        #pragma unroll
        for (int kh = 0; kh < 2; ++kh) {
            bf16x8 af[4], bfr[4];
            #pragma unroll
            for (int mi = 0; mi < 4; ++mi) {
                int row = wm * 64 + mi * 16 + l16;
                af[mi] = *(const bf16x8*)(As + row * 128 + ((l4 * 16 + kh * 64) ^ ((row & 7) << 4)));
            }
            #pragma unroll
            for (int ni = 0; ni < 4; ++ni) {
                int row = wn * 64 + ni * 16 + l16;
                bfr[ni] = *(const bf16x8*)(Bs + row * 128 + ((l4 * 16 + kh * 64) ^ ((row & 7) << 4)));
            }
            #pragma unroll
            for (int mi = 0; mi < 4; ++mi)
                #pragma unroll
                for (int ni = 0; ni < 4; ++ni)
                    acc[mi][ni] = __builtin_amdgcn_mfma_f32_16x16x32_bf16(
                        af[mi], bfr[ni], acc[mi][ni], 0, 0, 0);
        }
        __builtin_amdgcn_s_barrier();
    }

    if (write_f32) {
        #pragma unroll
        for (int ni = 0; ni < 4; ++ni) {
            int col = colBase + wn * 64 + ni * 16 + l16;
            float bb = bias ? bias[col] : 0.f;
            #pragma unroll
            for (int mi = 0; mi < 4; ++mi) {
                #pragma unroll
                for (int j = 0; j < 4; ++j) {
                    int row = rowBase + wm * 64 + mi * 16 + l4 * 4 + j;
                    ((float*)Cout)[(size_t)row * N + col] = acc[mi][ni][j] + bb;
                }
            }
        }
    } else {
        #pragma unroll
        for (int ni = 0; ni < 4; ++ni) {
            int col = colBase + wn * 64 + ni * 16 + l16;
            float bb = bias ? bias[col] : 0.f;
            float mul = (col < qscale_end) ? 0.125f : 1.0f;
            bool isV = vt && (col >= 2 * H);    // wave-uniform per ni
            #pragma unroll
            for (int mi = 0; mi < 4; ++mi) {
                int row0 = rowBase + wm * 64 + mi * 16 + l4 * 4;
                if (isV) {
                    // V fused transpose: 4 consecutive tokens = 4 consecutive s
                    us4 ov;
                    #pragma unroll
                    for (int j = 0; j < 4; ++j) ov[j] = f2bf(acc[mi][ni][j] + bb);
                    int dfull = col - 2 * H;
                    int hh = dfull >> 6, dd = dfull & 63;
                    int bq = row0 >> 10, s = row0 & 1023;
                    *(us4*)(&vt[((size_t)((bq * NH + hh) * 64 + dd)) * SEQ + s]) = ov;
                } else {
                    #pragma unroll
                    for (int j = 0; j < 4; ++j) {
                        int row = row0 + j;
                        ((unsigned short*)Cout)[(size_t)row * N + col] =
                            f2bf((acc[mi][ni][j] + bb) * mul);
                    }
                }
            }
        }
    }
}

// ---------------------------------------------------------------------------
// Flash attention v5: 32x32x16 MFMA, 4 waves x 32 q. Q pre-scaled 1/8 in QKV
// epilogue. Subtile-granular causal skip. T13 defer-rescale (THR=8).
// In-register P re-layout. K/V dbuf via global_load_lds(16) + counted
// vmcnt(4). XCD chunks, heavy-qb first.
// ---------------------------------------------------------------------------
__global__ __launch_bounds__(256, 4) void attn_mfma(
    const unsigned short* __restrict__ qkvb,
    const unsigned short* __restrict__ vt,
    unsigned short* __restrict__ aout)
{
    __shared__ char lds[32768];          // K dbuf 2x8K | V dbuf 2x8K
    char* Kbuf = lds;
    char* Vbuf = lds + 16384;
    int t = threadIdx.x;
    int l = t & 63, w = t >> 6;
    int l31 = l & 31, b5 = l >> 5;

    int lin = ((blockIdx.x & 7) * 192) + (blockIdx.x >> 3);   // XCD chunks
    int qb = 7 - (lin & 7);                                   // heavy first
    int bh = lin >> 3;
    int h = bh % NH, b = bh / NH;

    int wq = qb * 128 + w * 32;          // wave's 32 q rows
    int sw31 = (l31 & 7) << 4;
    int nt = 2 * qb + 2;
    int bhh = b * NH + h;
    const char* qkvc = (const char*)qkvb;
    const char* vtc  = (const char*)vt;

    // Q as B-fragments: col = q = l31, k = d = 16m + b5*8 + j  (pre-scaled)
    bf16x8 qB[4];
    {
        const unsigned short* qrow =
            qkvb + (size_t)(b * SEQ + wq + l31) * N3H + h * HD + b5 * 8;
        #pragma unroll
        for (int m = 0; m < 4; ++m) qB[m] = *(const bf16x8*)(qrow + m * 16);
    }

    auto STAGE = [&](int kt, int bi) {
        #pragma unroll
        for (int i = 0; i < 2; ++i) {
            int c = t + i * 256;
            int row = c >> 3;
            int src = ((c & 7) * 16) ^ ((row & 7) << 4);
            glds16(qkvc + ((size_t)(b * SEQ + kt * 64 + row) * N3H + H + h * HD) * 2 + src,
                   Kbuf + bi * 8192 + c * 16);
        }
        #pragma unroll
        for (int i = 0; i < 2; ++i) {
            int c = t + i * 256;
            int row = c >> 3;
            int src = ((c & 7) * 16) ^ ((row & 7) << 4);
            glds16(vtc + (((size_t)(bhh * 64 + row)) * SEQ + kt * 64) * 2 + src,
                   Vbuf + bi * 8192 + c * 16);
        }
    };

    STAGE(0, 0);
    __syncthreads();   // drains all vmem (Q regs + stage0); clean vmcnt state

    f32x16 o0, o1;
    #pragma unroll
    for (int r = 0; r < 16; ++r) { o0[r] = 0.f; o1[r] = 0.f; }
    float mrun = -1e30f, lrun = 0.f;

    for (int kt = 0; kt < nt; ++kt) {
        int bi = kt & 1;
        if (kt + 1 < nt) {
            STAGE(kt + 1, bi ^ 1);
            asm volatile("s_waitcnt vmcnt(4)" ::: "memory");
        } else {
            asm volatile("s_waitcnt vmcnt(0)" ::: "memory");
        }
        __builtin_amdgcn_s_barrier();

        int ktbase = kt * 64;
        if (ktbase <= wq + 31) {          // wave has unmasked work
            const char* Kb = Kbuf + bi * 8192;
            const char* Vb = Vbuf + bi * 8192;
            bool two = (ktbase + 32 <= wq + 31);   // upper 32-key half live?

            // S^T = K·Q^T : D rows = keys ((r&3)+8*(r>>2)+4*b5), cols = q
            f32x16 s0, s1;
            __builtin_amdgcn_s_setprio(1);
            {
                f32x16 a;
                #pragma unroll
                for (int r = 0; r < 16; ++r) a[r] = 0.f;
                #pragma unroll
                for (int m = 0; m < 4; ++m) {
                    bf16x8 kf = *(const bf16x8*)(Kb + l31 * 128 + ((m * 32 + b5 * 16) ^ sw31));
                    a = __builtin_amdgcn_mfma_f32_32x32x16_bf16(kf, qB[m], a, 0, 0, 0);
                }
                s0 = a;
            }
            if (two) {
                f32x16 a;
                #pragma unroll
                for (int r = 0; r < 16; ++r) a[r] = 0.f;
                #pragma unroll
                for (int m = 0; m < 4; ++m) {
                    bf16x8 kf = *(const bf16x8*)(Kb + (32 + l31) * 128 + ((m * 32 + b5 * 16) ^ sw31));
                    a = __builtin_amdgcn_mfma_f32_32x32x16_bf16(kf, qB[m], a, 0, 0, 0);
                }
                s1 = a;
            }
            __builtin_amdgcn_s_setprio(0);

            int q = wq + l31;
            if (ktbase + 31 > wq) {        // lower half needs masking
                #pragma unroll
                for (int r = 0; r < 16; ++r) {
                    int key = ktbase + (r & 3) + 8 * (r >> 2) + 4 * b5;
                    if (key > q) s0[r] = -3e38f;
                }
            }
            if (two && (ktbase + 63 > wq)) {
                #pragma unroll
                for (int r = 0; r < 16; ++r) {
                    int key = ktbase + 32 + (r & 3) + 8 * (r >> 2) + 4 * b5;
                    if (key > q) s1[r] = -3e38f;
                }
            }

            // online softmax: tree max + 1 xor32; T13 defer-rescale
            float m01 = fmaxf(s0[0], s0[1]), m23 = fmaxf(s0[2], s0[3]);
            float m45 = fmaxf(s0[4], s0[5]), m67 = fmaxf(s0[6], s0[7]);
            float m89 = fmaxf(s0[8], s0[9]), mab = fmaxf(s0[10], s0[11]);
            float mcd = fmaxf(s0[12], s0[13]), mef = fmaxf(s0[14], s0[15]);
            float mx = fmaxf(fmaxf(fmaxf(m01, m23), fmaxf(m45, m67)),
                             fmaxf(fmaxf(m89, mab), fmaxf(mcd, mef)));
            if (two) {
                float n01 = fmaxf(s1[0], s1[1]), n23 = fmaxf(s1[2], s1[3]);
                float n45 = fmaxf(s1[4], s1[5]), n67 = fmaxf(s1[6], s1[7]);
                float n89 = fmaxf(s1[8], s1[9]), nab = fmaxf(s1[10], s1[11]);
                float ncd = fmaxf(s1[12], s1[13]), nef = fmaxf(s1[14], s1[15]);
                mx = fmaxf(mx, fmaxf(fmaxf(fmaxf(n01, n23), fmaxf(n45, n67)),
                                     fmaxf(fmaxf(n89, nab), fmaxf(ncd, nef))));
            }
            mx = fmaxf(mx, __shfl_xor(mx, 32, 64));
            if (!__all(mx - mrun <= 8.f)) {
                float mnew = fmaxf(mrun, mx);
                float sc = __expf(mrun - mnew);
                mrun = mnew;
                lrun *= sc;
                #pragma unroll
                for (int r = 0; r < 16; ++r) { o0[r] *= sc; o1[r] *= sc; }
            }
            float rs = 0.f;
            #pragma unroll
            for (int r = 0; r < 16; ++r) {
                float p = __expf(s0[r] - mrun);
                s0[r] = p;
                rs += p;
            }
            if (two) {
                #pragma unroll
                for (int r = 0; r < 16; ++r) {
                    float p = __expf(s1[r] - mrun);
                    s1[r] = p;
                    rs += p;
                }
            }
            rs += __shfl_xor(rs, 32, 64);
            lrun += rs;

            // P D-layout -> B-fragments, in-register (1 xor32 swap / window)
            bf16x8 pB[4];
            #pragma unroll
            for (int wd = 0; wd < 4; ++wd) {
                if (wd >= 2 && !two) break;
                const f32x16& sv = (wd < 2) ? s0 : s1;
                int hf = (wd & 1) * 8;
                unsigned pk0 = (unsigned)f2bf(sv[hf + 0]) | ((unsigned)f2bf(sv[hf + 1]) << 16);
                unsigned pk1 = (unsigned)f2bf(sv[hf + 2]) | ((unsigned)f2bf(sv[hf + 3]) << 16);
                unsigned pk2 = (unsigned)f2bf(sv[hf + 4]) | ((unsigned)f2bf(sv[hf + 5]) << 16);
                unsigned pk3 = (unsigned)f2bf(sv[hf + 6]) | ((unsigned)f2bf(sv[hf + 7]) << 16);
                unsigned snd0 = b5 ? pk0 : pk2;
                unsigned snd1 = b5 ? pk1 : pk3;
                unsigned r0 = (unsigned)__shfl_xor((int)snd0, 32, 64);
                unsigned r1 = (unsigned)__shfl_xor((int)snd1, 32, 64);
                union { unsigned u[4]; bf16x8 v; } cvt;
                cvt.u[0] = b5 ? r0 : pk0;
                cvt.u[1] = b5 ? r1 : pk1;
                cvt.u[2] = b5 ? pk2 : r0;
                cvt.u[3] = b5 ? pk3 : r1;
                pB[wd] = cvt.v;
            }

            // O^T += V^T · P^T  (windows 2,3 skipped when upper half masked)
            __builtin_amdgcn_s_setprio(1);
            #pragma unroll
            for (int wd = 0; wd < 4; ++wd) {
                if (wd >= 2 && !two) break;
                bf16x8 v0 = *(const bf16x8*)(Vb + l31 * 128 + ((wd * 32 + b5 * 16) ^ sw31));
                o0 = __builtin_amdgcn_mfma_f32_32x32x16_bf16(v0, pB[wd], o0, 0, 0, 0);
                bf16x8 v1 = *(const bf16x8*)(Vb + (32 + l31) * 128 + ((wd * 32 + b5 * 16) ^ sw31));
                o1 = __builtin_amdgcn_mfma_f32_32x32x16_bf16(v1, pB[wd], o1, 0, 0, 0);
            }
            __builtin_amdgcn_s_setprio(0);
        }
        __builtin_amdgcn_s_barrier();
    }

    // epilogue: d = 32*half + 8g + 4b5 + j, q = wq + l31
    float inv = 1.f / lrun;
    size_t tok = (size_t)(b * SEQ + wq + l31);
    #pragma unroll
    for (int g = 0; g < 4; ++g) {
        us4 w0, w1;
        #pragma unroll
        for (int j = 0; j < 4; ++j) {
            w0[j] = f2bf(o0[g * 4 + j] * inv);
            w1[j] = f2bf(o1[g * 4 + j] * inv);
        }
        int d0 = g * 8 + b5 * 4;
        *(us4*)(&aout[tok * H + h * HD + d0]) = w0;
        *(us4*)(&aout[tok * H + h * HD + 32 + d0]) = w1;
    }
}

// ---------------------------------------------------------------------------
extern "C" void kernel_launch(void* const* d_in, const int* in_sizes, int n_in,
                              void* d_out, int out_size, void* d_ws, size_t ws_size,
                              hipStream_t stream) {
    const float* x      = (const float*)d_in[0];
    const float* W_qkv  = (const float*)d_in[1];
    const float* b_qkv  = (const float*)d_in[2];
    const float* W_proj = (const float*)d_in[3];
    const float* b_proj = (const float*)d_in[4];
    float* outp = (float*)d_out;

    char* ws = (char*)d_ws;
    unsigned short* xbf    = (unsigned short*)ws;  ws += (size_t)MTOK * H * 2;
    unsigned short* wqkvT  = (unsigned short*)ws;  ws += (size_t)N3H * H * 2;
    unsigned short* wprojT = (unsigned short*)ws;  ws += (size_t)H * H * 2;
    unsigned short* qkvb   = (unsigned short*)ws;  ws += (size_t)MTOK * N3H * 2;
    unsigned short* vtb    = (unsigned short*)ws;  ws += (size_t)BSZ * NH * 64 * SEQ * 2;
    unsigned short* aob    = (unsigned short*)ws;

    // fused preprocessing: cvt x + transpose/cvt both weights
    prep<<<6720, 256, 0, stream>>>(x, W_qkv, W_proj, xbf, wqkvT, wprojT);

    // QKV: [16384,768] @ [768,2304]; Q cols pre-scaled 0.125; V fused -> vtb
    gemm_bf16<<<(N3H / 128) * (MTOK / 128), 256, 0, stream>>>(
        xbf, wqkvT, b_qkv, qkvb, vtb, MTOK, N3H, H, 0, H);

    // attention: 1536 blocks, XCD-chunked, heavy-qb first
    attn_mfma<<<(SEQ / 128) * NH * BSZ, 256, 0, stream>>>(qkvb, vtb, aob);

    // proj: [16384,768] @ [768,768] -> fp32 out
    gemm_bf16<<<(H / 128) * (MTOK / 128), 256, 0, stream>>>(
        aob, wprojT, b_proj, (void*)outp, nullptr, MTOK, H, H, 1, 0);
}

// Round 8
// 315.739 us; speedup vs baseline: 1.2020x; 1.0102x over previous
//
#include <hip/hip_runtime.h>

#define H 768
#define NH 12
#define HD 64
#define BSZ 16
#define SEQ 1024
#define MTOK (BSZ * SEQ)   // 16384
#define N3H (3 * H)        // 2304

typedef __attribute__((ext_vector_type(8))) short bf16x8;
typedef __attribute__((ext_vector_type(4))) float f32x4;
typedef __attribute__((ext_vector_type(16))) float f32x16;
typedef __attribute__((ext_vector_type(8))) unsigned short us8;
typedef __attribute__((ext_vector_type(4))) unsigned short us4;

__device__ __forceinline__ unsigned short f2bf(float f) {
    union { float f; unsigned u; } v; v.f = f;
    unsigned r = v.u + 0x7fffu + ((v.u >> 16) & 1u);   // RNE
    return (unsigned short)(r >> 16);
}

typedef __attribute__((address_space(1))) const unsigned int gu32_t;
typedef __attribute__((address_space(3))) unsigned int lu32_t;
__device__ __forceinline__ void glds16(const void* g, void* l) {
    __builtin_amdgcn_global_load_lds((gu32_t*)g, (lu32_t*)l, 16, 0, 0);
}

// ---------------------------------------------------------------------------
// prep: fused {x fp32->bf16 convert | W_qkv transpose+cvt | W_proj transpose+cvt}
// blocks [0,6144): cvt x ; [6144,6576): W_qkv 36x12 tiles ; [6576,6720): W_proj
// ---------------------------------------------------------------------------
__global__ __launch_bounds__(256) void prep(
    const float* __restrict__ x,
    const float* __restrict__ Wqkv, const float* __restrict__ Wproj,
    unsigned short* __restrict__ xbf,
    unsigned short* __restrict__ wqkvT, unsigned short* __restrict__ wprojT)
{
    __shared__ float tile[64][65];
    int bx = blockIdx.x, t = threadIdx.x;

    if (bx < 6144) {                      // elementwise convert
        int i = bx * 2048 + t * 8;
        float4 a = *(const float4*)(x + i);
        float4 b = *(const float4*)(x + i + 4);
        us8 o;
        o[0]=f2bf(a.x); o[1]=f2bf(a.y); o[2]=f2bf(a.z); o[3]=f2bf(a.w);
        o[4]=f2bf(b.x); o[5]=f2bf(b.y); o[6]=f2bf(b.z); o[7]=f2bf(b.w);
        *(us8*)(xbf + i) = o;
        return;
    }

    const float* in; unsigned short* out; int Kd, Nd, n0, k0;
    if (bx < 6576) {
        int lb = bx - 6144;
        in = Wqkv; out = wqkvT; Kd = H; Nd = N3H;
        n0 = (lb % 36) * 64; k0 = (lb / 36) * 64;
    } else {
        int lb = bx - 6576;
        in = Wproj; out = wprojT; Kd = H; Nd = H;
        n0 = (lb % 12) * 64; k0 = (lb / 12) * 64;
    }
    #pragma unroll
    for (int r = 0; r < 4; ++r) {
        int kl = r * 16 + (t >> 4);
        float4 v = *(const float4*)(&in[(size_t)(k0 + kl) * Nd + n0 + (t & 15) * 4]);
        tile[kl][(t & 15) * 4 + 0] = v.x; tile[kl][(t & 15) * 4 + 1] = v.y;
        tile[kl][(t & 15) * 4 + 2] = v.z; tile[kl][(t & 15) * 4 + 3] = v.w;
    }
    __syncthreads();
    int nl = t >> 2, kc = (t & 3) * 16;
    us8 o0, o1;
    #pragma unroll
    for (int kk = 0; kk < 8; ++kk) o0[kk] = f2bf(tile[kc + kk][nl]);
    #pragma unroll
    for (int kk = 0; kk < 8; ++kk) o1[kk] = f2bf(tile[kc + 8 + kk][nl]);
    size_t ob = (size_t)(n0 + nl) * Kd + k0 + kc;
    *(us8*)(&out[ob]) = o0;
    *(us8*)(&out[ob + 8]) = o1;
}

// ---------------------------------------------------------------------------
// bf16 MFMA GEMM: C[M,N] = A[M,K] @ BT[N,K]^T + bias
// 128x128 tile, BK=64, single 32K LDS buffer, 4 waves (each 64x64), 16x16 MFMA.
// QKV mode (vt != null): V-range cols written transposed to vt ONLY; Q cols
// pre-scaled by 0.125. Proj mode (write_f32): fp32 C.
// ---------------------------------------------------------------------------
__global__ __launch_bounds__(256) void gemm_bf16(
    const unsigned short* __restrict__ A, const unsigned short* __restrict__ BT,
    const float* __restrict__ bias, void* __restrict__ Cout,
    unsigned short* __restrict__ vt,
    int M, int N, int K, int write_f32, int qscale_end)
{
    __shared__ char lds[32768];
    char* As = lds;
    char* Bs = lds + 16384;
    const char* Ac = (const char*)A;
    const char* Bc = (const char*)BT;
    int t = threadIdx.x;
    int l = t & 63, w = t >> 6;
    int l16 = l & 15, l4 = l >> 4;
    int wm = w >> 1, wn = w & 1;

    int chunk = (int)gridDim.x >> 3;
    int lin = (blockIdx.x & 7) * chunk + (blockIdx.x >> 3);
    int nbx = N >> 7;
    int bx = lin % nbx, by = lin / nbx;
    int rowBase = by * 128, colBase = bx * 128;

    f32x4 acc[4][4];
    #pragma unroll
    for (int i = 0; i < 4; ++i)
        #pragma unroll
        for (int j = 0; j < 4; ++j) acc[i][j] = (f32x4){0, 0, 0, 0};

    for (int k0 = 0; k0 < K; k0 += 64) {
        #pragma unroll
        for (int i = 0; i < 4; ++i) {
            int c = t + i * 256;             // 0..1023
            int row = c >> 3;
            int src = ((c & 7) * 16) ^ ((row & 7) << 4);
            glds16(Ac + ((size_t)(rowBase + row) * K + k0) * 2 + src, As + c * 16);
            glds16(Bc + ((size_t)(colBase + row) * K + k0) * 2 + src, Bs + c * 16);
        }
        asm volatile("s_waitcnt vmcnt(0)" ::: "memory");
        __builtin_amdgcn_s_barrier();

        #pragma unroll
        for (int kh = 0; kh < 2; ++kh) {
            bf16x8 af[4], bfr[4];
            #pragma unroll
            for (int mi = 0; mi < 4; ++mi) {
                int row = wm * 64 + mi * 16 + l16;
                af[mi] = *(const bf16x8*)(As + row * 128 + ((l4 * 16 + kh * 64) ^ ((row & 7) << 4)));
            }
            #pragma unroll
            for (int ni = 0; ni < 4; ++ni) {
                int row = wn * 64 + ni * 16 + l16;
                bfr[ni] = *(const bf16x8*)(Bs + row * 128 + ((l4 * 16 + kh * 64) ^ ((row & 7) << 4)));
            }
            #pragma unroll
            for (int mi = 0; mi < 4; ++mi)
                #pragma unroll
                for (int ni = 0; ni < 4; ++ni)
                    acc[mi][ni] = __builtin_amdgcn_mfma_f32_16x16x32_bf16(
                        af[mi], bfr[ni], acc[mi][ni], 0, 0, 0);
        }
        __builtin_amdgcn_s_barrier();
    }

    if (write_f32) {
        #pragma unroll
        for (int ni = 0; ni < 4; ++ni) {
            int col = colBase + wn * 64 + ni * 16 + l16;
            float bb = bias ? bias[col] : 0.f;
            #pragma unroll
            for (int mi = 0; mi < 4; ++mi) {
                #pragma unroll
                for (int j = 0; j < 4; ++j) {
                    int row = rowBase + wm * 64 + mi * 16 + l4 * 4 + j;
                    ((float*)Cout)[(size_t)row * N + col] = acc[mi][ni][j] + bb;
                }
            }
        }
    } else {
        #pragma unroll
        for (int ni = 0; ni < 4; ++ni) {
            int col = colBase + wn * 64 + ni * 16 + l16;
            float bb = bias ? bias[col] : 0.f;
            float mul = (col < qscale_end) ? 0.125f : 1.0f;
            bool isV = vt && (col >= 2 * H);    // wave-uniform per ni
            #pragma unroll
            for (int mi = 0; mi < 4; ++mi) {
                int row0 = rowBase + wm * 64 + mi * 16 + l4 * 4;
                if (isV) {
                    // V fused transpose: 4 consecutive tokens = 4 consecutive s
                    us4 ov;
                    #pragma unroll
                    for (int j = 0; j < 4; ++j) ov[j] = f2bf(acc[mi][ni][j] + bb);
                    int dfull = col - 2 * H;
                    int hh = dfull >> 6, dd = dfull & 63;
                    int bq = row0 >> 10, s = row0 & 1023;
                    *(us4*)(&vt[((size_t)((bq * NH + hh) * 64 + dd)) * SEQ + s]) = ov;
                } else {
                    #pragma unroll
                    for (int j = 0; j < 4; ++j) {
                        int row = row0 + j;
                        ((unsigned short*)Cout)[(size_t)row * N + col] =
                            f2bf((acc[mi][ni][j] + bb) * mul);
                    }
                }
            }
        }
    }
}

// ---------------------------------------------------------------------------
// Flash attention (round-5 proven body, VGPR-64 bucket): 32x32x16 MFMA,
// 4 waves x 32 q. Q pre-scaled 1/8 in QKV epilogue. T13 defer-rescale (THR=8).
// Straight-line both 32-key subtiles (no data-dependent skip — round-6 lesson:
// branches between MFMA clusters cost more than the skipped work).
// In-register P re-layout (1 shfl_xor(32)/window). K/V dbuf via
// global_load_lds(16) + counted vmcnt(4). XCD chunks, heavy-qb first.
// ---------------------------------------------------------------------------
__global__ __launch_bounds__(256, 4) void attn_mfma(
    const unsigned short* __restrict__ qkvb,
    const unsigned short* __restrict__ vt,
    unsigned short* __restrict__ aout)
{
    __shared__ char lds[32768];          // K dbuf 2x8K | V dbuf 2x8K
    char* Kbuf = lds;
    char* Vbuf = lds + 16384;
    int t = threadIdx.x;
    int l = t & 63, w = t >> 6;
    int l31 = l & 31, b5 = l >> 5;

    int lin = ((blockIdx.x & 7) * 192) + (blockIdx.x >> 3);   // XCD chunks
    int qb = 7 - (lin & 7);                                   // heavy first
    int bh = lin >> 3;
    int h = bh % NH, b = bh / NH;

    int wq = qb * 128 + w * 32;          // wave's 32 q rows
    int sw31 = (l31 & 7) << 4;
    int nt = 2 * qb + 2;
    int bhh = b * NH + h;
    const char* qkvc = (const char*)qkvb;
    const char* vtc  = (const char*)vt;

    // Q as B-fragments: col = q = l31, k = d = 16m + b5*8 + j  (pre-scaled)
    bf16x8 qB[4];
    {
        const unsigned short* qrow =
            qkvb + (size_t)(b * SEQ + wq + l31) * N3H + h * HD + b5 * 8;
        #pragma unroll
        for (int m = 0; m < 4; ++m) qB[m] = *(const bf16x8*)(qrow + m * 16);
    }

    auto STAGE = [&](int kt, int bi) {
        #pragma unroll
        for (int i = 0; i < 2; ++i) {
            int c = t + i * 256;
            int row = c >> 3;
            int src = ((c & 7) * 16) ^ ((row & 7) << 4);
            glds16(qkvc + ((size_t)(b * SEQ + kt * 64 + row) * N3H + H + h * HD) * 2 + src,
                   Kbuf + bi * 8192 + c * 16);
        }
        #pragma unroll
        for (int i = 0; i < 2; ++i) {
            int c = t + i * 256;
            int row = c >> 3;
            int src = ((c & 7) * 16) ^ ((row & 7) << 4);
            glds16(vtc + (((size_t)(bhh * 64 + row)) * SEQ + kt * 64) * 2 + src,
                   Vbuf + bi * 8192 + c * 16);
        }
    };

    STAGE(0, 0);
    __syncthreads();   // drains all vmem (Q regs + stage0); clean vmcnt state

    f32x16 o0, o1;
    #pragma unroll
    for (int r = 0; r < 16; ++r) { o0[r] = 0.f; o1[r] = 0.f; }
    float mrun = -1e30f, lrun = 0.f;

    for (int kt = 0; kt < nt; ++kt) {
        int bi = kt & 1;
        if (kt + 1 < nt) {
            STAGE(kt + 1, bi ^ 1);
            asm volatile("s_waitcnt vmcnt(4)" ::: "memory");
        } else {
            asm volatile("s_waitcnt vmcnt(0)" ::: "memory");
        }
        __builtin_amdgcn_s_barrier();

        int ktbase = kt * 64;
        if (ktbase <= wq + 31) {          // wave has unmasked work
            const char* Kb = Kbuf + bi * 8192;
            const char* Vb = Vbuf + bi * 8192;

            // S^T = K·Q^T : D rows = keys ((r&3)+8*(r>>2)+4*b5), cols = q
            f32x16 s[2];
            __builtin_amdgcn_s_setprio(1);
            #pragma unroll
            for (int st2 = 0; st2 < 2; ++st2) {
                f32x16 a;
                #pragma unroll
                for (int r = 0; r < 16; ++r) a[r] = 0.f;
                #pragma unroll
                for (int m = 0; m < 4; ++m) {
                    int row = st2 * 32 + l31;
                    bf16x8 kf = *(const bf16x8*)(Kb + row * 128 + ((m * 32 + b5 * 16) ^ sw31));
                    a = __builtin_amdgcn_mfma_f32_32x32x16_bf16(kf, qB[m], a, 0, 0, 0);
                }
                s[st2] = a;
            }
            __builtin_amdgcn_s_setprio(0);

            if (ktbase + 63 > wq) {       // causal mask needed
                int q = wq + l31;
                #pragma unroll
                for (int st2 = 0; st2 < 2; ++st2)
                    #pragma unroll
                    for (int r = 0; r < 16; ++r) {
                        int key = ktbase + st2 * 32 + (r & 3) + 8 * (r >> 2) + 4 * b5;
                        if (key > q) s[st2][r] = -3e38f;
                    }
            }

            // online softmax: 31 in-lane fmax + 1 xor32; T13 defer-rescale
            float mx = s[0][0];
            #pragma unroll
            for (int r = 1; r < 16; ++r) mx = fmaxf(mx, s[0][r]);
            #pragma unroll
            for (int r = 0; r < 16; ++r) mx = fmaxf(mx, s[1][r]);
            mx = fmaxf(mx, __shfl_xor(mx, 32, 64));
            if (!__all(mx - mrun <= 8.f)) {
                float mnew = fmaxf(mrun, mx);
                float sc = __expf(mrun - mnew);
                mrun = mnew;
                lrun *= sc;
                #pragma unroll
                for (int r = 0; r < 16; ++r) { o0[r] *= sc; o1[r] *= sc; }
            }
            float rs = 0.f;
            #pragma unroll
            for (int st2 = 0; st2 < 2; ++st2)
                #pragma unroll
                for (int r = 0; r < 16; ++r) {
                    float p = __expf(s[st2][r] - mrun);
                    s[st2][r] = p;
                    rs += p;
                }
            rs += __shfl_xor(rs, 32, 64);
            lrun += rs;

            // P D-layout -> B-fragments, in-register (1 xor32 swap / window)
            bf16x8 pB[4];
            #pragma unroll
            for (int wd = 0; wd < 4; ++wd) {
                int st2 = wd >> 1, hf = (wd & 1) * 8;
                unsigned pk0 = (unsigned)f2bf(s[st2][hf + 0]) | ((unsigned)f2bf(s[st2][hf + 1]) << 16);
                unsigned pk1 = (unsigned)f2bf(s[st2][hf + 2]) | ((unsigned)f2bf(s[st2][hf + 3]) << 16);
                unsigned pk2 = (unsigned)f2bf(s[st2][hf + 4]) | ((unsigned)f2bf(s[st2][hf + 5]) << 16);
                unsigned pk3 = (unsigned)f2bf(s[st2][hf + 6]) | ((unsigned)f2bf(s[st2][hf + 7]) << 16);
                unsigned snd0 = b5 ? pk0 : pk2;
                unsigned snd1 = b5 ? pk1 : pk3;
                unsigned r0 = (unsigned)__shfl_xor((int)snd0, 32, 64);
                unsigned r1 = (unsigned)__shfl_xor((int)snd1, 32, 64);
                union { unsigned u[4]; bf16x8 v; } cvt;
                cvt.u[0] = b5 ? r0 : pk0;
                cvt.u[1] = b5 ? r1 : pk1;
                cvt.u[2] = b5 ? pk2 : r0;
                cvt.u[3] = b5 ? pk3 : r1;
                pB[wd] = cvt.v;
            }

            // O^T += V^T · P^T : A = V^T (rows = d), B = P (cols = q)
            __builtin_amdgcn_s_setprio(1);
            #pragma unroll
            for (int wd = 0; wd < 4; ++wd) {
                bf16x8 v0 = *(const bf16x8*)(Vb + l31 * 128 + ((wd * 32 + b5 * 16) ^ sw31));
                o0 = __builtin_amdgcn_mfma_f32_32x32x16_bf16(v0, pB[wd], o0, 0, 0, 0);
                bf16x8 v1 = *(const bf16x8*)(Vb + (32 + l31) * 128 + ((wd * 32 + b5 * 16) ^ sw31));
                o1 = __builtin_amdgcn_mfma_f32_32x32x16_bf16(v1, pB[wd], o1, 0, 0, 0);
            }
            __builtin_amdgcn_s_setprio(0);
        }
        __builtin_amdgcn_s_barrier();
    }

    // epilogue: d = 32*half + 8g + 4b5 + j, q = wq + l31
    float inv = 1.f / lrun;
    size_t tok = (size_t)(b * SEQ + wq + l31);
    #pragma unroll
    for (int g = 0; g < 4; ++g) {
        us4 w0, w1;
        #pragma unroll
        for (int j = 0; j < 4; ++j) {
            w0[j] = f2bf(o0[g * 4 + j] * inv);
            w1[j] = f2bf(o1[g * 4 + j] * inv);
        }
        int d0 = g * 8 + b5 * 4;
        *(us4*)(&aout[tok * H + h * HD + d0]) = w0;
        *(us4*)(&aout[tok * H + h * HD + 32 + d0]) = w1;
    }
}

// ---------------------------------------------------------------------------
extern "C" void kernel_launch(void* const* d_in, const int* in_sizes, int n_in,
                              void* d_out, int out_size, void* d_ws, size_t ws_size,
                              hipStream_t stream) {
    const float* x      = (const float*)d_in[0];
    const float* W_qkv  = (const float*)d_in[1];
    const float* b_qkv  = (const float*)d_in[2];
    const float* W_proj = (const float*)d_in[3];
    const float* b_proj = (const float*)d_in[4];
    float* outp = (float*)d_out;

    char* ws = (char*)d_ws;
    unsigned short* xbf    = (unsigned short*)ws;  ws += (size_t)MTOK * H * 2;
    unsigned short* wqkvT  = (unsigned short*)ws;  ws += (size_t)N3H * H * 2;
    unsigned short* wprojT = (unsigned short*)ws;  ws += (size_t)H * H * 2;
    unsigned short* qkvb   = (unsigned short*)ws;  ws += (size_t)MTOK * N3H * 2;
    unsigned short* vtb    = (unsigned short*)ws;  ws += (size_t)BSZ * NH * 64 * SEQ * 2;
    unsigned short* aob    = (unsigned short*)ws;

    // fused preprocessing: cvt x + transpose/cvt both weights
    prep<<<6720, 256, 0, stream>>>(x, W_qkv, W_proj, xbf, wqkvT, wprojT);

    // QKV: [16384,768] @ [768,2304]; Q cols pre-scaled 0.125; V fused -> vtb
    gemm_bf16<<<(N3H / 128) * (MTOK / 128), 256, 0, stream>>>(
        xbf, wqkvT, b_qkv, qkvb, vtb, MTOK, N3H, H, 0, H);

    // attention: 1536 blocks, XCD-chunked, heavy-qb first
    attn_mfma<<<(SEQ / 128) * NH * BSZ, 256, 0, stream>>>(qkvb, vtb, aob);

    // proj: [16384,768] @ [768,768] -> fp32 out
    gemm_bf16<<<(H / 128) * (MTOK / 128), 256, 0, stream>>>(
        aob, wprojT, b_proj, (void*)outp, nullptr, MTOK, H, H, 1, 0);
}